// Round 2
// baseline (139.466 us; speedup 1.0000x reference)
//
#include <hip/hip_runtime.h>

namespace {
constexpr int B = 16, C = 19, H = 512, W = 512;
constexpr int TPB = 128;                     // 2 waves; thread t owns cols 4t..4t+3 (full W)
constexpr int H_CHUNK = 64;
constexpr int NHC = H / H_CHUNK;             // 8
constexpr int TILES = B * NHC;               // 128 (b, hc) tiles
constexpr int NXCD = 8;
constexpr int TILES_PER_XCD = TILES / NXCD;  // 16
constexpr int TOTAL_BLOCKS = TILES * C;      // 2432
constexpr float SCALE = 1.0f / (float)((long long)B * H * W);
}

struct RowS {
    float4 d, s;    // input plane: col-diff (x[j+1]-x[j-1]) and col-sum (x[j-1]+2x[j]+x[j+1])
    float4 md, ms;  // one-hot mask: same aggregates
};

__global__ void zero_out_kernel(float* out) { *out = 0.0f; }

__global__ __launch_bounds__(TPB) void edge_loss_kernel(
    const float* __restrict__ X,   // [B,C,H,W] f32
    const int*   __restrict__ T,   // [B,H,W] int32 labels
    float* __restrict__ out)
{
    // XCD-aware decode: hardware round-robins blockIdx across 8 XCDs (bid%8).
    // Put all 19 c-blocks of one (b,hc) tile consecutively on ONE XCD so the
    // target tile is fetched into that XCD's L2 once, not 8 times.
    int i = (int)blockIdx.x;
    const int xcd = i & (NXCD - 1);
    const int j   = i >> 3;                    // slot sequence on this XCD
    const int c   = j % C;                     // fastest: same tile, different class
    const int tl  = j / C;                     // 0..15
    const int tile = xcd * TILES_PER_XCD + tl; // 0..127
    const int b   = tile / NHC;
    const int hc  = tile % NHC;

    const int tid  = (int)threadIdx.x;
    const int lane = tid & 63;
    const int w0   = tid << 2;                 // first of 4 owned columns
    const int h0   = hc * H_CHUNK;

    const float* __restrict__ Xs = X + (size_t)(b * C + c) * (size_t)(H * W);
    const int*   __restrict__ Ts = T + (size_t)b * (size_t)(H * W);

    // wave-boundary halo columns (zero-pad at image borders is free: shfl result replaced by 0)
    const bool needL = (lane == 0)  && (w0 > 0);
    const bool needR = (lane == 63) && (w0 + 4 < W);
    const int  colL  = needL ? (w0 - 1) : 0;
    const int  colR  = needR ? (w0 + 4) : 0;

    RowS r0, r1, r2;
    float acc = 0.0f;

    auto load_row = [&](RowS& r, int hrow) {
        if (hrow < 0 || hrow >= H) {           // block-uniform branch
            r.d = r.s = r.md = r.ms = make_float4(0.f, 0.f, 0.f, 0.f);
            return;
        }
        const float* xr = Xs + (size_t)hrow * W;
        const int*   tr = Ts + (size_t)hrow * W;
        const float4 xv = *reinterpret_cast<const float4*>(xr + w0);
        const int4   tv = *reinterpret_cast<const int4*>(tr + w0);
        const float eL  = needL ? xr[colL] : 0.0f;           // exec-masked scalar loads
        const float eR  = needR ? xr[colR] : 0.0f;
        const float eLm = needL ? ((tr[colL] == c) ? 1.0f : 0.0f) : 0.0f;
        const float eRm = needR ? ((tr[colR] == c) ? 1.0f : 0.0f) : 0.0f;

        float Lx = __shfl_up(xv.w, 1, 64);   if (lane == 0)  Lx = eL;
        float Rx = __shfl_down(xv.x, 1, 64); if (lane == 63) Rx = eR;

        const float m0 = (tv.x == c) ? 1.0f : 0.0f;
        const float m1 = (tv.y == c) ? 1.0f : 0.0f;
        const float m2 = (tv.z == c) ? 1.0f : 0.0f;
        const float m3 = (tv.w == c) ? 1.0f : 0.0f;
        float Lm = __shfl_up(m3, 1, 64);     if (lane == 0)  Lm = eLm;
        float Rm = __shfl_down(m0, 1, 64);   if (lane == 63) Rm = eRm;

        r.d.x = xv.y - Lx;   r.d.y = xv.z - xv.x;
        r.d.z = xv.w - xv.y; r.d.w = Rx   - xv.z;
        r.s.x = fmaf(2.f, xv.x, Lx + xv.y);
        r.s.y = fmaf(2.f, xv.y, xv.x + xv.z);
        r.s.z = fmaf(2.f, xv.z, xv.y + xv.w);
        r.s.w = fmaf(2.f, xv.w, xv.z + Rx);

        r.md.x = m1 - Lm; r.md.y = m2 - m0;
        r.md.z = m3 - m1; r.md.w = Rm - m2;
        r.ms.x = fmaf(2.f, m0, Lm + m1);
        r.ms.y = fmaf(2.f, m1, m0 + m2);
        r.ms.z = fmaf(2.f, m2, m1 + m3);
        r.ms.w = fmaf(2.f, m3, m2 + Rm);
    };

    int h = h0;
    auto body = [&](const RowS& ra, const RowS& rb, RowS& rc) {
        load_row(rc, h + 1);
#define COMP(f)                                                      \
        {                                                            \
            float gx = fmaf(2.f, rb.d.f,  ra.d.f  + rc.d.f);         \
            float gy = rc.s.f  - ra.s.f;                             \
            float hx = fmaf(2.f, rb.md.f, ra.md.f + rc.md.f);        \
            float hy = rc.ms.f - ra.ms.f;                            \
            float dd = (fabsf(gx) + fabsf(gy))                       \
                     - (fabsf(hx) + fabsf(hy));                      \
            acc = fmaf(dd, dd, acc);                                 \
        }
        COMP(x) COMP(y) COMP(z) COMP(w)
#undef COMP
        ++h;
    };

    // prologue: rows h0-1 and h0
    load_row(r0, h0 - 1);
    load_row(r1, h0);

    // 64 output rows = 21 register-rotating triples + 1
    for (int t = 0; t < (H_CHUNK / 3); ++t) {
        body(r0, r1, r2);
        body(r1, r2, r0);
        body(r2, r0, r1);
    }
    body(r0, r1, r2);   // row h0+63

    // reduce: wave shuffle, then 2 waves via LDS, one atomic per block
    #pragma unroll
    for (int off = 32; off > 0; off >>= 1)
        acc += __shfl_down(acc, off, 64);

    __shared__ float wsum[TPB / 64];
    const int wid = tid >> 6;
    if (lane == 0) wsum[wid] = acc;
    __syncthreads();
    if (tid == 0) atomicAdd(out, (wsum[0] + wsum[1]) * SCALE);
}

extern "C" void kernel_launch(void* const* d_in, const int* in_sizes, int n_in,
                              void* d_out, int out_size, void* d_ws, size_t ws_size,
                              hipStream_t stream) {
    (void)in_sizes; (void)n_in; (void)d_ws; (void)ws_size; (void)out_size;
    const float* X = (const float*)d_in[0];
    const int*   T = (const int*)d_in[1];
    float* out = (float*)d_out;

    zero_out_kernel<<<1, 1, 0, stream>>>(out);
    edge_loss_kernel<<<TOTAL_BLOCKS, TPB, 0, stream>>>(X, T, out);
}